// Round 3
// baseline (1118.965 us; speedup 1.0000x reference)
//
#include <hip/hip_runtime.h>
#include <stdint.h>

#define TOKENS 8192
#define IN_F   4096
#define OUT_F  11008
#define GROUPSIZE 128

// ---- GEMM geometry: 256x256, BK=64, 2-barrier free-run schedule ----
#define BM 256
#define BN 256
#define BK 64
#define NT  (IN_F / BK)        // 64 K-tiles
#define NBM (TOKENS / BM)      // 32
#define NBN (OUT_F / BN)       // 43
#define NWG (NBM * NBN)        // 1376 = 8 * 172 (bijective XCD swizzle ok)

typedef __attribute__((ext_vector_type(8)))  short          bf16x8;
typedef __attribute__((ext_vector_type(4)))  float          f32x4;
typedef __attribute__((ext_vector_type(8)))  unsigned short u16x8;
typedef __attribute__((ext_vector_type(16))) unsigned short u16x16;

static __device__ __forceinline__ unsigned short f2bf(float f) {
    union { float f; unsigned int u; } v; v.f = f;
    unsigned int u = v.u;
    u += 0x7fffu + ((u >> 16) & 1u);   // round-to-nearest-even
    return (unsigned short)(u >> 16);
}

// ---------------------------------------------------------------- x -> bf16
__global__ void cvt_x_kernel(const float* __restrict__ x,
                             unsigned short* __restrict__ xb) {
    int i = (blockIdx.x * 256 + threadIdx.x) * 8;
    const float4* p = (const float4*)(x + i);
    float4 a = p[0];
    float4 b = p[1];
    u16x8 o;
    o[0] = f2bf(a.x); o[1] = f2bf(a.y); o[2] = f2bf(a.z); o[3] = f2bf(a.w);
    o[4] = f2bf(b.x); o[5] = f2bf(b.y); o[6] = f2bf(b.z); o[7] = f2bf(b.w);
    *(u16x8*)(xb + i) = o;
}

// ------------------------------------------- dequant int4 -> bf16, W_t[N][K]
__global__ void dequant_kernel(const int* __restrict__ qweight,
                               const int* __restrict__ qzeros,
                               const float* __restrict__ scales,
                               unsigned short* __restrict__ Wt) {
    const int t   = threadIdx.x;
    const int n   = blockIdx.x * 32 + (t >> 3);
    const int kp0 = blockIdx.y * 16 + (t & 7) * 2;
    const int g   = blockIdx.y;                // uniform per block
    const float s  = scales[g * OUT_F + n];
    const int   zq = ((qzeros[g * (OUT_F / 8) + (n >> 3)] >> (4 * (n & 7))) & 0xF) + 1;
    const float zs = (float)zq * s;            // w = nib*s - zs
    const int qw0 = qweight[(size_t)kp0 * OUT_F + n];
    const int qw1 = qweight[(size_t)(kp0 + 1) * OUT_F + n];
    u16x16 o;
#pragma unroll
    for (int j = 0; j < 8; ++j) {
        o[j]     = f2bf(fmaf((float)((qw0 >> (4 * j)) & 0xF), s, -zs));
        o[j + 8] = f2bf(fmaf((float)((qw1 >> (4 * j)) & 0xF), s, -zs));
    }
    *(u16x16*)(Wt + (size_t)n * IN_F + kp0 * 8) = o;
}

// -------------------------------------------------------------- bf16 GEMM
// C[M][N] = A[M][K] * Bt[N][K]^T + bias
// 256^2 tile, BK=64, 8 waves (2M x 4N). LDS = 3xA + 2xB buffers = 160 KiB.
// 2 barriers per K-tile (mid: B-buffer handoff; boundary: tile handoff).
// A staged 2 tiles ahead (no intra-tile hazard); B 2 tiles ahead into the
// buffer freed at the mid barrier. Boundary vmcnt(8) covers loads issued a
// full tile earlier -> no latency stall. Waves free-run between barriers.
#define GLD16(gp, lp)                                                        \
    __builtin_amdgcn_global_load_lds(                                        \
        (const __attribute__((address_space(1))) unsigned int*)(gp),         \
        (__attribute__((address_space(3))) unsigned int*)(lp), 16, 0, 0)

#define BARRIER() do {                                                       \
    asm volatile("" ::: "memory");                                           \
    __builtin_amdgcn_s_barrier();                                            \
    asm volatile("" ::: "memory");                                           \
} while (0)

#define LGKM(n) do {                                                         \
    asm volatile("s_waitcnt lgkmcnt(" #n ")" ::: "memory");                  \
    __builtin_amdgcn_sched_barrier(0);                                       \
} while (0)

__global__ __launch_bounds__(512, 2) void gemm_bias_kernel(
    const unsigned short* __restrict__ A,   // [TOKENS][IN_F] bf16
    const unsigned short* __restrict__ Bt,  // [OUT_F][IN_F]  bf16
    const float* __restrict__ bias,
    float* __restrict__ C) {
    extern __shared__ char smem_c[];   // 160 KiB: A0|A1|A2|B0|B1 (32 KiB each)

    const int tid = threadIdx.x;
    const int l   = tid & 63;
    const int w   = tid >> 6;          // 8 waves
    const int wr  = w >> 2;            // 0..1  (M half)
    const int wc  = w & 3;             // 0..3  (N quarter)

    // T1: bijective XCD swizzle
    const int bid = blockIdx.x;
    const int swz = (bid & 7) * (NWG / 8) + (bid >> 3);
    const int m0  = (swz / NBN) * BM;
    const int n0  = (swz % NBN) * BN;

    // ---- staging (global_load_lds: linear LDS dst, pre-swizzled global src)
    const int sperm = ((l & 7) ^ (l >> 3)) * 8;   // source col offset, elements
    const unsigned short* aG = A  + (size_t)(m0 + w * 16 + (l >> 3)) * IN_F + sperm;
    const unsigned short* bG = Bt + (size_t)(n0 + w * 16 + (l >> 3)) * IN_F + sperm;
    const int sOff = w * 2048 + l * 16;           // LDS byte offset in buffer

#define STAGE_A4(lbase, tt) do {                                             \
    GLD16(aG + (size_t)(tt) * 64,                      (lbase) + sOff);      \
    GLD16(aG + (size_t)8   * IN_F + (size_t)(tt) * 64, (lbase) + sOff + 1024);\
    GLD16(aG + (size_t)128 * IN_F + (size_t)(tt) * 64, (lbase) + sOff + 16384);\
    GLD16(aG + (size_t)136 * IN_F + (size_t)(tt) * 64, (lbase) + sOff + 16384 + 1024);\
} while (0)
#define STAGE_B4(lbase, tt) do {                                             \
    GLD16(bG + (size_t)(tt) * 64,                      (lbase) + sOff);      \
    GLD16(bG + (size_t)8   * IN_F + (size_t)(tt) * 64, (lbase) + sOff + 1024);\
    GLD16(bG + (size_t)128 * IN_F + (size_t)(tt) * 64, (lbase) + sOff + 16384);\
    GLD16(bG + (size_t)136 * IN_F + (size_t)(tt) * 64, (lbase) + sOff + 16384 + 1024);\
} while (0)

    // ---- fragment reads (ds_read_b128, XOR-swizzled: slot=(kg+4ks)^(row&7))
    const int c0   = (((l >> 4) ^ (l & 7)) * 8);   // ks=0 col offset, elements
    const int c1   = c0 ^ 32;                      // ks=1
    const int arow = (wr * 128 + (l & 15)) * 64;
    const int brow = (wc * 64  + (l & 15)) * 64;

    f32x4  acc[8][4] = {};
    bf16x8 aP0[2], aP1[2], aQ0[2], aQ1[2], bfr[4][2];

#define RDB4(p) do {                                                         \
    bfr[0][0] = *(const bf16x8*)&(p)[brow + 0 * 1024 + c0];                  \
    bfr[0][1] = *(const bf16x8*)&(p)[brow + 0 * 1024 + c1];                  \
    bfr[1][0] = *(const bf16x8*)&(p)[brow + 1 * 1024 + c0];                  \
    bfr[1][1] = *(const bf16x8*)&(p)[brow + 1 * 1024 + c1];                  \
    bfr[2][0] = *(const bf16x8*)&(p)[brow + 2 * 1024 + c0];                  \
    bfr[2][1] = *(const bf16x8*)&(p)[brow + 2 * 1024 + c1];                  \
    bfr[3][0] = *(const bf16x8*)&(p)[brow + 3 * 1024 + c0];                  \
    bfr[3][1] = *(const bf16x8*)&(p)[brow + 3 * 1024 + c1];                  \
} while (0)
#define RDA2(p, mi, d0, d1) do {                                             \
    d0[0] = *(const bf16x8*)&(p)[arow + (mi) * 1024 + c0];                   \
    d0[1] = *(const bf16x8*)&(p)[arow + (mi) * 1024 + c1];                   \
    d1[0] = *(const bf16x8*)&(p)[arow + ((mi) + 1) * 1024 + c0];             \
    d1[1] = *(const bf16x8*)&(p)[arow + ((mi) + 1) * 1024 + c1];             \
} while (0)
#define MMX(Af, mi, nj, ks)                                                  \
    acc[mi][nj] = __builtin_amdgcn_mfma_f32_16x16x32_bf16(                   \
        Af[ks], bfr[nj][ks], acc[mi][nj], 0, 0, 0)
#define QUADX(A0, A1, e) do {                                                \
    __builtin_amdgcn_s_setprio(1);                                           \
    MMX(A0, e, 0, 0); MMX(A0, e, 1, 0); MMX(A0, e, 2, 0); MMX(A0, e, 3, 0);  \
    MMX(A1, (e)+1, 0, 0); MMX(A1, (e)+1, 1, 0); MMX(A1, (e)+1, 2, 0); MMX(A1, (e)+1, 3, 0); \
    MMX(A0, e, 0, 1); MMX(A0, e, 1, 1); MMX(A0, e, 2, 1); MMX(A0, e, 3, 1);  \
    MMX(A1, (e)+1, 0, 1); MMX(A1, (e)+1, 1, 1); MMX(A1, (e)+1, 2, 1); MMX(A1, (e)+1, 3, 1); \
    __builtin_amdgcn_s_setprio(0);                                           \
} while (0)

    // LDS buffer byte offsets (rotated; uniform scalars, no arrays -> no scratch)
    int aOff0 = 0, aOff1 = 32768, aOff2 = 65536;
    int bOff0 = 98304, bOff1 = 131072;

    // ---- prologue: stage T0, T1 fully; vmcnt(8) -> T0 landed
    STAGE_A4(smem_c + aOff0, 0); STAGE_B4(smem_c + bOff0, 0);
    STAGE_A4(smem_c + aOff1, 1); STAGE_B4(smem_c + bOff1, 1);
    asm volatile("s_waitcnt vmcnt(8)" ::: "memory");
    __builtin_amdgcn_sched_barrier(0);
    BARRIER();

#pragma unroll 1
    for (int t = 0; t < NT; ++t) {
        const unsigned short* pA = (const unsigned short*)(smem_c + aOff0);
        const unsigned short* pB = (const unsigned short*)(smem_c + bOff0);

        // --- S1: read all B frags; stage A(t+2) (no hazard: buf last read t-1)
        RDB4(pB);
        if (t + 2 < NT) STAGE_A4(smem_c + aOff2, t + 2);
        LGKM(0);                 // own B-reads retired
        BARRIER();               // mid: ALL waves' B-reads of this buf retired
        // current B buffer is now write-safe for B(t+2)
        if (t + 2 < NT) STAGE_B4(smem_c + bOff0, t + 2);

        // --- free-run: A-pair pipelined reads + 4 MFMA quads, own-pace lgkm
        RDA2(pA, 0, aP0, aP1);
        RDA2(pA, 2, aQ0, aQ1);
        LGKM(4);  QUADX(aP0, aP1, 0);
        RDA2(pA, 4, aP0, aP1);
        LGKM(4);  QUADX(aQ0, aQ1, 2);
        RDA2(pA, 6, aQ0, aQ1);
        LGKM(4);  QUADX(aP0, aP1, 4);
        LGKM(0);  QUADX(aQ0, aQ1, 6);

        // --- boundary: A(t+1),B(t+1) (issued a full tile ago) must be in LDS
        if (t < NT - 2)
            asm volatile("s_waitcnt vmcnt(8)" ::: "memory");
        else
            asm volatile("s_waitcnt vmcnt(0)" ::: "memory");
        __builtin_amdgcn_sched_barrier(0);
        BARRIER();

        // rotate buffers
        int ta = aOff0; aOff0 = aOff1; aOff1 = aOff2; aOff2 = ta;
        int tb = bOff0; bOff0 = bOff1; bOff1 = tb;
    }

    // ---- epilogue: C/D layout col=lane&15, row=(lane>>4)*4+reg
    // nontemporal: keep the 360MB C stream out of L3 so A/B stay resident
    const int col = l & 15;
    const int r0  = (l >> 4) * 4;
#pragma unroll
    for (int nj = 0; nj < 4; ++nj) {
        const int n = n0 + wc * 64 + nj * 16 + col;
        const float bv = bias[n];
#pragma unroll
        for (int mi = 0; mi < 8; ++mi) {
            const int m = m0 + wr * 128 + mi * 16 + r0;
#pragma unroll
            for (int r = 0; r < 4; ++r)
                __builtin_nontemporal_store(acc[mi][nj][r] + bv,
                                            &C[(size_t)(m + r) * OUT_F + n]);
        }
    }
}

// ---------------------------------------------- zero-workspace fallback
__global__ __launch_bounds__(256) void fallback_kernel(
    const float* __restrict__ x, const int* __restrict__ qweight,
    const int* __restrict__ qzeros, const float* __restrict__ scales,
    const float* __restrict__ bias, float* __restrict__ C) {
    const int n = blockIdx.x * 16 + (threadIdx.x & 15);
    const int m = blockIdx.y * 16 + (threadIdx.x >> 4);
    float acc = 0.f;
    const float* xr = x + (size_t)m * IN_F;
    for (int g = 0; g < IN_F / GROUPSIZE; ++g) {
        const float s  = scales[g * OUT_F + n];
        const float zs = s * (float)(((qzeros[g * (OUT_F / 8) + (n >> 3)]
                                       >> (4 * (n & 7))) & 0xF) + 1);
        for (int kp = g * 16; kp < g * 16 + 16; ++kp) {
            const int qw = qweight[kp * OUT_F + n];
#pragma unroll
            for (int j = 0; j < 8; ++j) {
                const float w = fmaf((float)((qw >> (4 * j)) & 0xF), s, -zs);
                acc = fmaf(xr[kp * 8 + j], w, acc);
            }
        }
    }
    C[(size_t)m * OUT_F + n] = acc + bias[n];
}

extern "C" void kernel_launch(void* const* d_in, const int* in_sizes, int n_in,
                              void* d_out, int out_size, void* d_ws, size_t ws_size,
                              hipStream_t stream) {
    const float* x       = (const float*)d_in[0];
    const int*   qweight = (const int*)  d_in[1];
    const int*   qzeros  = (const int*)  d_in[2];
    const float* scales  = (const float*)d_in[3];
    // d_in[4] = g_idx (arange(IN_F)//GROUPSIZE; computed inline)
    const float* bias    = (const float*)d_in[5];
    float* out = (float*)d_out;

    const size_t xb_bytes = (size_t)TOKENS * IN_F * sizeof(unsigned short); // 67.1 MB
    const size_t wt_bytes = (size_t)OUT_F  * IN_F * sizeof(unsigned short); // 90.2 MB

    static int lds_ok = -1;
    if (lds_ok < 0) {
        hipError_t e = hipFuncSetAttribute((const void*)gemm_bias_kernel,
                                           hipFuncAttributeMaxDynamicSharedMemorySize,
                                           163840);
        lds_ok = (e == hipSuccess) ? 1 : 0;
    }

    if (ws_size >= xb_bytes + wt_bytes && lds_ok == 1) {
        unsigned short* xb = (unsigned short*)d_ws;
        unsigned short* Wt = (unsigned short*)((char*)d_ws + xb_bytes);
        cvt_x_kernel<<<(TOKENS * IN_F) / (256 * 8), 256, 0, stream>>>(x, xb);
        dequant_kernel<<<dim3(OUT_F / 32, IN_F / 8 / 16), 256, 0, stream>>>(
            qweight, qzeros, scales, Wt);
        gemm_bias_kernel<<<NWG, 512, 163840, stream>>>(xb, Wt, bias, out);
    } else {
        fallback_kernel<<<dim3(OUT_F / 16, TOKENS / 16), 256, 0, stream>>>(
            x, qweight, qzeros, scales, bias, out);
    }
}

// Round 4
// 1088.834 us; speedup vs baseline: 1.0277x; 1.0277x over previous
//
#include <hip/hip_runtime.h>
#include <stdint.h>

#define TOKENS 8192
#define IN_F   4096
#define OUT_F  11008
#define GROUPSIZE 128

// ---- GEMM geometry: 256x256, BK=64, balanced 4-phase schedule (R2) ----
#define BM 256
#define BN 256
#define BK 64
#define NT  (IN_F / BK)        // 64 K-tiles
#define NBM (TOKENS / BM)      // 32
#define NBN (OUT_F / BN)       // 43
#define NWG (NBM * NBN)        // 1376 = 8 * 172 (bijective XCD swizzle ok)

typedef __attribute__((ext_vector_type(8)))  short          bf16x8;
typedef __attribute__((ext_vector_type(4)))  float          f32x4;
typedef __attribute__((ext_vector_type(8)))  unsigned short u16x8;
typedef __attribute__((ext_vector_type(16))) unsigned short u16x16;

static __device__ __forceinline__ unsigned short f2bf(float f) {
    union { float f; unsigned int u; } v; v.f = f;
    unsigned int u = v.u;
    u += 0x7fffu + ((u >> 16) & 1u);   // round-to-nearest-even
    return (unsigned short)(u >> 16);
}

// ---------------------------------------------------------------- x -> bf16
__global__ void cvt_x_kernel(const float* __restrict__ x,
                             unsigned short* __restrict__ xb) {
    int i = (blockIdx.x * 256 + threadIdx.x) * 8;
    const float4* p = (const float4*)(x + i);
    float4 a = p[0];
    float4 b = p[1];
    u16x8 o;
    o[0] = f2bf(a.x); o[1] = f2bf(a.y); o[2] = f2bf(a.z); o[3] = f2bf(a.w);
    o[4] = f2bf(b.x); o[5] = f2bf(b.y); o[6] = f2bf(b.z); o[7] = f2bf(b.w);
    *(u16x8*)(xb + i) = o;
}

// ------------------------------------------- dequant int4 -> bf16, W_t[N][K]
// Coalesced rewrite: lane -> n (consecutive int32 of qweight row), thread owns
// column n for all 16 packed rows of group g. qweight reads fully coalesced
// (1 KiB/wave/row, was 16x overfetch); writes: 256 contiguous B per thread.
// grid (OUT_F/256, N_GROUPS=32), 256 threads.
__global__ void dequant_kernel(const int* __restrict__ qweight,
                               const int* __restrict__ qzeros,
                               const float* __restrict__ scales,
                               unsigned short* __restrict__ Wt) {
    const int t  = threadIdx.x;
    const int n  = blockIdx.x * 256 + t;
    const int g  = blockIdx.y;
    const float s  = scales[g * OUT_F + n];
    const int   zq = ((qzeros[g * (OUT_F / 8) + (n >> 3)] >> (4 * (n & 7))) & 0xF) + 1;
    const float zs = (float)zq * s;            // w = nib*s - zs

    const int* qrow = qweight + (size_t)(g * 16) * OUT_F + n;
    unsigned short* wrow = Wt + (size_t)n * IN_F + g * GROUPSIZE;

    int qw[16];
#pragma unroll
    for (int r = 0; r < 16; ++r)
        qw[r] = qrow[(size_t)r * OUT_F];       // coalesced across lanes

#pragma unroll
    for (int r = 0; r < 16; r += 2) {
        u16x16 o;
#pragma unroll
        for (int j = 0; j < 8; ++j) {
            o[j]     = f2bf(fmaf((float)((qw[r]     >> (4 * j)) & 0xF), s, -zs));
            o[j + 8] = f2bf(fmaf((float)((qw[r + 1] >> (4 * j)) & 0xF), s, -zs));
        }
        *(u16x16*)(wrow + r * 8) = o;          // 32B, contiguous per thread
    }
}

// -------------------------------------------------------------- bf16 GEMM
// C[M][N] = A[M][K] * Bt[N][K]^T + bias   (R2 schedule, best measured)
// 256^2 tile, BK=64, 8 waves (2M x 4N), 128 KiB LDS double-buffer.
// Balanced 4-phase/K-tile: per-phase ds_reads 12,4,4,4; 16 MFMA per phase.
// Stage stream: A(t+1)->other buf in P0/P1, B(t+2)->current buf in P2/P3.
#define GLD16(gp, lp)                                                        \
    __builtin_amdgcn_global_load_lds(                                        \
        (const __attribute__((address_space(1))) unsigned int*)(gp),         \
        (__attribute__((address_space(3))) unsigned int*)(lp), 16, 0, 0)

#define BARRIER() do {                                                       \
    asm volatile("" ::: "memory");                                           \
    __builtin_amdgcn_s_barrier();                                            \
    asm volatile("" ::: "memory");                                           \
} while (0)

#define LGKM0() do {                                                         \
    asm volatile("s_waitcnt lgkmcnt(0)" ::: "memory");                       \
    __builtin_amdgcn_sched_barrier(0);                                       \
} while (0)

__global__ __launch_bounds__(512, 2) void gemm_bias_kernel(
    const unsigned short* __restrict__ A,   // [TOKENS][IN_F] bf16
    const unsigned short* __restrict__ Bt,  // [OUT_F][IN_F]  bf16
    const float* __restrict__ bias,
    float* __restrict__ C) {
    extern __shared__ char smem_c[];   // 128 KiB: {A|B} x {buf0|buf1}

    const int tid = threadIdx.x;
    const int l   = tid & 63;
    const int w   = tid >> 6;          // 8 waves
    const int wr  = w >> 2;            // 0..1  (M half)
    const int wc  = w & 3;             // 0..3  (N quarter)

    // T1: bijective XCD swizzle
    const int bid = blockIdx.x;
    const int swz = (bid & 7) * (NWG / 8) + (bid >> 3);
    const int m0  = (swz / NBN) * BM;
    const int n0  = (swz % NBN) * BN;

    // ---- staging (global_load_lds: linear LDS dst, pre-swizzled global src)
    const int sperm = ((l & 7) ^ (l >> 3)) * 8;   // source col offset, elements
    const unsigned short* aG = A  + (size_t)(m0 + w * 16 + (l >> 3)) * IN_F + sperm;
    const unsigned short* bG = Bt + (size_t)(n0 + w * 16 + (l >> 3)) * IN_F + sperm;
    char* sA = smem_c + w * 2048 + l * 16;        // + b*65536 + h*16384 + i*1024
    char* sB = sA + 32768;

#define STAGE_A(b, h, tt) do {                                               \
    GLD16(aG + (size_t)((h) * 128    ) * IN_F + (tt) * 64,                   \
          sA + (b) * 65536 + (h) * 16384);                                   \
    GLD16(aG + (size_t)((h) * 128 + 8) * IN_F + (tt) * 64,                   \
          sA + (b) * 65536 + (h) * 16384 + 1024);                            \
} while (0)
#define STAGE_B(b, h, tt) do {                                               \
    GLD16(bG + (size_t)((h) * 128    ) * IN_F + (tt) * 64,                   \
          sB + (b) * 65536 + (h) * 16384);                                   \
    GLD16(bG + (size_t)((h) * 128 + 8) * IN_F + (tt) * 64,                   \
          sB + (b) * 65536 + (h) * 16384 + 1024);                            \
} while (0)

    // ---- fragment reads (ds_read_b128, XOR-swizzled: slot=(kg+4ks)^(row&7))
    const unsigned short* LAe = (const unsigned short*)smem_c;
    const unsigned short* LBe = (const unsigned short*)(smem_c + 32768);
    const int c0   = (((l >> 4) ^ (l & 7)) * 8);   // ks=0 col offset, elements
    const int c1   = c0 ^ 32;                      // ks=1
    const int arow = (wr * 128 + (l & 15)) * 64;
    const int brow = (wc * 64  + (l & 15)) * 64;

    f32x4  acc[8][4] = {};
    bf16x8 a0[2], a1[2], bfr[4][2];

#define RDA_PAIR(p, mi) do {                                                 \
    a0[0] = *(const bf16x8*)&(p)[arow + (mi) * 1024 + c0];                   \
    a0[1] = *(const bf16x8*)&(p)[arow + (mi) * 1024 + c1];                   \
    a1[0] = *(const bf16x8*)&(p)[arow + ((mi) + 1) * 1024 + c0];             \
    a1[1] = *(const bf16x8*)&(p)[arow + ((mi) + 1) * 1024 + c1];             \
} while (0)
#define RDB(p, nj) do {                                                      \
    bfr[nj][0] = *(const bf16x8*)&(p)[brow + (nj) * 1024 + c0];              \
    bfr[nj][1] = *(const bf16x8*)&(p)[brow + (nj) * 1024 + c1];              \
} while (0)
#define MM0(mi, nj, ks)                                                      \
    acc[mi][nj] = __builtin_amdgcn_mfma_f32_16x16x32_bf16(                   \
        a0[ks], bfr[nj][ks], acc[mi][nj], 0, 0, 0)
#define MM1(mi, nj, ks)                                                      \
    acc[mi][nj] = __builtin_amdgcn_mfma_f32_16x16x32_bf16(                   \
        a1[ks], bfr[nj][ks], acc[mi][nj], 0, 0, 0)
#define QUADP(e) do {                                                        \
    __builtin_amdgcn_s_setprio(1);                                           \
    MM0(e,0,0); MM0(e,1,0); MM0(e,2,0); MM0(e,3,0);                          \
    MM1((e)+1,0,0); MM1((e)+1,1,0); MM1((e)+1,2,0); MM1((e)+1,3,0);          \
    MM0(e,0,1); MM0(e,1,1); MM0(e,2,1); MM0(e,3,1);                          \
    MM1((e)+1,0,1); MM1((e)+1,1,1); MM1((e)+1,2,1); MM1((e)+1,3,1);          \
    __builtin_amdgcn_s_setprio(0);                                           \
} while (0)

    // ---- prologue: T0 fully staged (buf0) + B(1) (buf1) in flight
    STAGE_A(0, 0, 0); STAGE_A(0, 1, 0);
    STAGE_B(0, 0, 0); STAGE_B(0, 1, 0);
    STAGE_B(1, 0, 1); STAGE_B(1, 1, 1);
    asm volatile("s_waitcnt vmcnt(4)" ::: "memory");  // A(0),B(0) landed
    __builtin_amdgcn_sched_barrier(0);
    BARRIER();

    for (int t = 0; t < NT; ++t) {
        const int bt = t & 1;
        const int bo = bt ^ 1;
        const unsigned short* pA = LAe + bt * 32768;
        const unsigned short* pB = LBe + bt * 32768;

        // P0: 12 reads (all B + A-pair 0) ; stage A0(t+1) -> other buf
        RDB(pB, 0); RDB(pB, 1); RDB(pB, 2); RDB(pB, 3);
        RDA_PAIR(pA, 0);
        if (t + 1 < NT) STAGE_A(bo, 0, t + 1);
        BARRIER();
        LGKM0();
        QUADP(0);
        BARRIER();

        // P1: 4 reads (A-pair 2) ; stage A1(t+1)
        RDA_PAIR(pA, 2);
        if (t + 1 < NT) STAGE_A(bo, 1, t + 1);
        BARRIER();
        LGKM0();
        QUADP(2);
        BARRIER();

        // P2: 4 reads (A-pair 4) ; stage B0(t+2) -> current buf (B reads done)
        RDA_PAIR(pA, 4);
        if (t + 2 < NT) STAGE_B(bt, 0, t + 2);
        BARRIER();
        LGKM0();
        QUADP(4);
        BARRIER();

        // P3: 4 reads (A-pair 6) ; stage B1(t+2) ; counted vmcnt at boundary
        RDA_PAIR(pA, 6);
        if (t + 2 < NT) STAGE_B(bt, 1, t + 2);
        BARRIER();
        LGKM0();
        QUADP(6);
        if (t < NT - 2)
            asm volatile("s_waitcnt vmcnt(4)" ::: "memory"); // A(t+1),B(t+1) in
        else if (t == NT - 2)
            asm volatile("s_waitcnt vmcnt(0)" ::: "memory"); // drain tail
        __builtin_amdgcn_sched_barrier(0);
        BARRIER();
    }

    // ---- epilogue: C/D layout col=lane&15, row=(lane>>4)*4+reg
    const int col = l & 15;
    const int r0  = (l >> 4) * 4;
#pragma unroll
    for (int nj = 0; nj < 4; ++nj) {
        const int n = n0 + wc * 64 + nj * 16 + col;
        const float bv = bias[n];
#pragma unroll
        for (int mi = 0; mi < 8; ++mi) {
            const int m = m0 + wr * 128 + mi * 16 + r0;
#pragma unroll
            for (int r = 0; r < 4; ++r)
                C[(size_t)(m + r) * OUT_F + n] = acc[mi][nj][r] + bv;
        }
    }
}

// ---------------------------------------------- zero-workspace fallback
__global__ __launch_bounds__(256) void fallback_kernel(
    const float* __restrict__ x, const int* __restrict__ qweight,
    const int* __restrict__ qzeros, const float* __restrict__ scales,
    const float* __restrict__ bias, float* __restrict__ C) {
    const int n = blockIdx.x * 16 + (threadIdx.x & 15);
    const int m = blockIdx.y * 16 + (threadIdx.x >> 4);
    float acc = 0.f;
    const float* xr = x + (size_t)m * IN_F;
    for (int g = 0; g < IN_F / GROUPSIZE; ++g) {
        const float s  = scales[g * OUT_F + n];
        const float zs = s * (float)(((qzeros[g * (OUT_F / 8) + (n >> 3)]
                                       >> (4 * (n & 7))) & 0xF) + 1);
        for (int kp = g * 16; kp < g * 16 + 16; ++kp) {
            const int qw = qweight[kp * OUT_F + n];
#pragma unroll
            for (int j = 0; j < 8; ++j) {
                const float w = fmaf((float)((qw >> (4 * j)) & 0xF), s, -zs);
                acc = fmaf(xr[kp * 8 + j], w, acc);
            }
        }
    }
    C[(size_t)m * OUT_F + n] = acc + bias[n];
}

extern "C" void kernel_launch(void* const* d_in, const int* in_sizes, int n_in,
                              void* d_out, int out_size, void* d_ws, size_t ws_size,
                              hipStream_t stream) {
    const float* x       = (const float*)d_in[0];
    const int*   qweight = (const int*)  d_in[1];
    const int*   qzeros  = (const int*)  d_in[2];
    const float* scales  = (const float*)d_in[3];
    // d_in[4] = g_idx (arange(IN_F)//GROUPSIZE; computed inline)
    const float* bias    = (const float*)d_in[5];
    float* out = (float*)d_out;

    const size_t xb_bytes = (size_t)TOKENS * IN_F * sizeof(unsigned short); // 67.1 MB
    const size_t wt_bytes = (size_t)OUT_F  * IN_F * sizeof(unsigned short); // 90.2 MB

    if (ws_size >= xb_bytes + wt_bytes) {
        static bool attr_done = false;
        if (!attr_done) {
            (void)hipFuncSetAttribute((const void*)gemm_bias_kernel,
                                      hipFuncAttributeMaxDynamicSharedMemorySize,
                                      131072);
            attr_done = true;
        }
        unsigned short* xb = (unsigned short*)d_ws;
        unsigned short* Wt = (unsigned short*)((char*)d_ws + xb_bytes);
        cvt_x_kernel<<<(TOKENS * IN_F) / (256 * 8), 256, 0, stream>>>(x, xb);
        dequant_kernel<<<dim3(OUT_F / 256, IN_F / GROUPSIZE), 256, 0, stream>>>(
            qweight, qzeros, scales, Wt);
        gemm_bias_kernel<<<NWG, 512, 131072, stream>>>(xb, Wt, bias, out);
    } else {
        fallback_kernel<<<dim3(OUT_F / 16, TOKENS / 16), 256, 0, stream>>>(
            x, qweight, qzeros, scales, bias, out);
    }
}